// Round 7
// baseline (3337.147 us; speedup 1.0000x reference)
//
#include <hip/hip_runtime.h>
#include <stdint.h>

// MyVanillaRNN: B=64, T=512, INPUT=512, HIDDEN=1024
// out = concat( pre[B,T,H] (f32), h_final[B,H] (f32) )

typedef __attribute__((ext_vector_type(8))) short bf16x8;
typedef __attribute__((ext_vector_type(4))) float f32x4;

__device__ __forceinline__ uint32_t f2bf(float f) {
    union { float f; uint32_t u; } v; v.f = f;
    return (v.u + 0x7FFFu + ((v.u >> 16) & 1u)) >> 16;   // RNE
}
__device__ __forceinline__ uint32_t pack2bf(float a, float b) {
    return f2bf(a) | (f2bf(b) << 16);
}
__device__ __forceinline__ float fast_tanh(float x) {
    const float xc = fminf(fmaxf(x, -15.f), 15.f);
    const float e  = __expf(2.f * xc);
    return (e - 1.f) * __builtin_amdgcn_rcpf(e + 1.f);
}
// L1-bypassing load; allowed to HIT the XCD's shared L2. Fresh for same-XCD
// plain stores once they drain to L2. Cross-XCD freshness NOT guaranteed ->
// poll loop interleaves agent-scope rounds on the slow buffer for liveness.
__device__ __forceinline__ uint32_t ld_sc0(const uint32_t* p) {
    uint32_t v;
    asm volatile("global_load_dword %0, %1, off sc0"
                 : "=v"(v) : "v"((uint64_t)(uintptr_t)p));
    return v;
}

// ---------------------------------------------------------------------------
// Phase 1: out[m][n] = sum_k x[m][k]*Wx[n][k] + bx[n] + bh[n]
// M=32768, N=1024, K=512.  128x128 tile, BK=64, 4 waves, bf16 MFMA.
// ---------------------------------------------------------------------------
__global__ __launch_bounds__(256) void xproj_gemm(
    const float* __restrict__ x, const float* __restrict__ Wx,
    const float* __restrict__ bx, const float* __restrict__ bh,
    float* __restrict__ out)
{
    __shared__ __align__(16) uint8_t Ab[128 * 128];
    __shared__ __align__(16) uint8_t Bb[128 * 128];

    const int tid  = threadIdx.x;
    const int lane = tid & 63;
    const int wid  = tid >> 6;
    const int wm = wid >> 1, wn = wid & 1;
    const int m0 = (int)(blockIdx.x >> 3) * 128;
    const int n0 = (int)(blockIdx.x & 7) * 128;

    f32x4 acc[4][4];
    #pragma unroll
    for (int i = 0; i < 4; ++i)
        #pragma unroll
        for (int j = 0; j < 4; ++j) acc[i][j] = (f32x4){0.f, 0.f, 0.f, 0.f};

    const int sr = tid >> 4;
    const int sk = (tid & 15) << 2;

    for (int k0 = 0; k0 < 512; k0 += 64) {
        __syncthreads();
        #pragma unroll
        for (int p = 0; p < 8; ++p) {
            const int r = sr + p * 16;
            const float4 a = *(const float4*)(x  + (size_t)(m0 + r) * 512 + k0 + sk);
            const float4 b = *(const float4*)(Wx + (size_t)(n0 + r) * 512 + k0 + sk);
            const int byo = r * 128 + ((sk << 1) ^ ((r & 7) << 4));
            *(uint2*)(Ab + byo) = make_uint2(pack2bf(a.x, a.y), pack2bf(a.z, a.w));
            *(uint2*)(Bb + byo) = make_uint2(pack2bf(b.x, b.y), pack2bf(b.z, b.w));
        }
        __syncthreads();
        #pragma unroll
        for (int kt = 0; kt < 2; ++kt) {
            bf16x8 af[4], bfr[4];
            const int kb = (kt << 6) + ((lane >> 4) << 4);
            #pragma unroll
            for (int q = 0; q < 4; ++q) {
                const int ar = wm * 64 + q * 16 + (lane & 15);
                const int br = wn * 64 + q * 16 + (lane & 15);
                af[q]  = *(const bf16x8*)(Ab + ar * 128 + (kb ^ ((ar & 7) << 4)));
                bfr[q] = *(const bf16x8*)(Bb + br * 128 + (kb ^ ((br & 7) << 4)));
            }
            #pragma unroll
            for (int mt = 0; mt < 4; ++mt)
                #pragma unroll
                for (int nt = 0; nt < 4; ++nt)
                    acc[mt][nt] = __builtin_amdgcn_mfma_f32_16x16x32_bf16(
                        af[mt], bfr[nt], acc[mt][nt], 0, 0, 0);
        }
    }

    #pragma unroll
    for (int nt = 0; nt < 4; ++nt) {
        const int n = n0 + wn * 64 + nt * 16 + (lane & 15);
        const float bias = bx[n] + bh[n];
        #pragma unroll
        for (int mt = 0; mt < 4; ++mt) {
            const int mb = m0 + wm * 64 + mt * 16 + ((lane >> 4) << 2);
            #pragma unroll
            for (int i = 0; i < 4; ++i)
                out[(size_t)(mb + i) * 1024 + n] = acc[mt][nt][i] + bias;
        }
    }
}

// ---------------------------------------------------------------------------
// Phase 2: persistent scan with HW-VERIFIED same-XCD groups.
// dual mode: 256 blocks (1/CU via 96KB LDS). Each block reads HW_REG_XCC_ID
// and claims (group = own XCD, slot 0..7) via atomicCAS -> all 8 blocks of a
// group provably share one XCD L2. Group g: batches [8g,+8). Slot nb: cols
// [128nb,+128). Extra blocks wait on a claimed-counter then exit (or rescue-
// claim unclaimed slots after ~110us if XCC_ID is broken -> correctness never
// depends on placement).
// h exchange, tagged words (bf16<<16 | (t+1)):
//   FAST: plain volatile stores -> producer's (== consumer's) XCD L2;
//         polled with sc0 loads (L1-bypass, L2-hit).
//   SLOW: agent-scope atomic stores to a 2nd buffer (fabric-coherent);
//         poll interleaves agent rounds (round>=4, odd) for liveness.
// Own 128 cols never cross global (parity double-buffered LDS tile).
// xp software-pipelined one step ahead. Fixed MFMA order -> deterministic.
// ---------------------------------------------------------------------------
__global__ __launch_bounds__(512, 1) void rnn_scan(
    const float* __restrict__ h0, const float* __restrict__ Wh,
    float* __restrict__ out, float* __restrict__ hfin,
    uint32_t* __restrict__ claim,    // [65] (dual only): 64 slot flags + count
    uint32_t* __restrict__ fbuf,     // [2][64][1024] fast
    uint32_t* __restrict__ sbuf,     // [2][64][1024] slow (== fbuf if !dual)
    int dual)
{
    // rows 0..7 (x2048B) per parity used; rest pads LDS > 80KB => 1 block/CU.
    __shared__ __align__(16) uint8_t htile[2][49152];
    __shared__ int s_role[2];

    const int tid = threadIdx.x;

    // --- role assignment
    if (tid == 0) {
        int gg = -1, ss = -1;
        if (dual) {
            uint32_t xcc = 0;
            asm volatile("s_getreg_b32 %0, hwreg(HW_REG_XCC_ID)" : "=s"(xcc));
            xcc &= 7u;
            const int st = ((int)blockIdx.x >> 3) & 7;   // stagger first attempt
            for (int a = 0; a < 8; ++a) {
                const int s2 = (st + a) & 7;
                if (atomicCAS(&claim[xcc * 8 + s2], 0u, 1u) == 0u) {
                    gg = (int)xcc; ss = s2; break;
                }
            }
            if (gg >= 0) {
                atomicAdd(&claim[64], 1u);
            } else {
                // non-worker: wait for all 64 claims, or rescue after ~110us
                for (int w = 0; w < 64; ++w) {
                    __builtin_amdgcn_s_sleep(127);
                    if (__hip_atomic_load(&claim[64], __ATOMIC_RELAXED,
                                          __HIP_MEMORY_SCOPE_AGENT) >= 64u) break;
                    if (w >= 32) {   // rescue sweep (XCC_ID broken / uneven)
                        for (int k = 0; k < 64 && gg < 0; ++k)
                            if (atomicCAS(&claim[k], 0u, 1u) == 0u) { gg = k >> 3; ss = k & 7; }
                        if (gg >= 0) atomicAdd(&claim[64], 1u);
                        break;
                    }
                }
            }
        } else {
            if ((int)blockIdx.x < 64) { gg = (int)blockIdx.x & 7; ss = (int)blockIdx.x >> 3; }
        }
        s_role[0] = gg; s_role[1] = ss;
    }
    __syncthreads();
    const int g  = s_role[0];
    const int nb = s_role[1];
    if (g < 0) return;

    const int lane = tid & 63;
    const int wid  = tid >> 6;          // 0..7
    const int gb0  = g * 8;             // batch base
    const int col  = nb * 128 + wid * 16 + (lane & 15);   // own output col
    const int r4b  = ((lane >> 4) & 1) << 2;              // 0/4 batch sub-base

    // --- Wh B-fragments: own col, full K. frag kt elem j <-> k=kt*32+(lane>>4)*8+j
    bf16x8 whf[32];
    {
        const float* wp = Wh + (size_t)col * 1024 + ((lane >> 4) << 3);
        #pragma unroll
        for (int kt = 0; kt < 32; ++kt) {
            const float4 w0 = *(const float4*)(wp + kt * 32);
            const float4 w1 = *(const float4*)(wp + kt * 32 + 4);
            bf16x8 f;
            f[0] = (short)f2bf(w0.x); f[1] = (short)f2bf(w0.y);
            f[2] = (short)f2bf(w0.z); f[3] = (short)f2bf(w0.w);
            f[4] = (short)f2bf(w1.x); f[5] = (short)f2bf(w1.y);
            f[6] = (short)f2bf(w1.z); f[7] = (short)f2bf(w1.w);
            whf[kt] = f;
        }
    }

    // --- init: publish own slice of h0 (tag 1, parity 0) + own LDS fill
    {
        const int colI = nb * 128 + lane * 2;   // two adjacent own cols
        const uint32_t u0 = f2bf(h0[(size_t)(gb0 + wid) * 1024 + colI]);
        const uint32_t u1 = f2bf(h0[(size_t)(gb0 + wid) * 1024 + colI + 1]);
        const int idx = (gb0 + wid) * 1024 + colI;
        if (dual) {
            ((volatile uint32_t*)fbuf)[idx]     = (u0 << 16) | 1u;
            ((volatile uint32_t*)fbuf)[idx + 1] = (u1 << 16) | 1u;
        }
        __hip_atomic_store(&sbuf[idx],     (u0 << 16) | 1u, __ATOMIC_RELAXED, __HIP_MEMORY_SCOPE_AGENT);
        __hip_atomic_store(&sbuf[idx + 1], (u1 << 16) | 1u, __ATOMIC_RELAXED, __HIP_MEMORY_SCOPE_AGENT);
        *(uint32_t*)(htile[0] + wid * 2048 + ((colI * 2) ^ (wid << 4))) = u0 | (u1 << 16);
    }

    // --- poll indices: 7 remote blocks x 2 words; batch row = wid
    const int pb  = wid;
    const int pc0 = lane * 2;
    int ridx[7];
    #pragma unroll
    for (int r = 0; r < 7; ++r) {
        const int rbk = (nb + 1 + r) & 7;
        ridx[r] = (gb0 + pb) * 1024 + rbk * 128 + pc0;
    }

    // --- xp preload for t=0
    float xpv[4];
    #pragma unroll
    for (int i = 0; i < 4; ++i)
        xpv[i] = out[((size_t)(gb0 + r4b + i) * 512 + 0) * 1024 + col];

    for (int t = 0; t < 512; ++t) {
        const int cur = t & 1;
        uint32_t* const fsrc = fbuf + cur * 65536;
        uint32_t* const fdst = fbuf + (cur ^ 1) * 65536;
        uint32_t* const ssrc = sbuf + cur * 65536;
        uint32_t* const sdst = sbuf + (cur ^ 1) * 65536;
        const uint32_t exptag = (uint32_t)(t + 1);
        const uint32_t ntag   = exptag + 1;

        // --- phase A: poll 7 remote slices. Fast sc0 rounds (local L2);
        // agent-scope rounds interleaved from round 4 for liveness.
        uint32_t v[14];
        int round = 0;
        while (true) {
            const bool slow = (!dual) || ((round >= 4) && (round & 1));
            if (!slow) {
                #pragma unroll
                for (int r = 0; r < 7; ++r) {
                    v[2 * r]     = ld_sc0(&fsrc[ridx[r]]);
                    v[2 * r + 1] = ld_sc0(&fsrc[ridx[r] + 1]);
                }
                asm volatile("s_waitcnt vmcnt(0)" ::: "memory");
                __builtin_amdgcn_sched_barrier(0);
            } else {
                #pragma unroll
                for (int r = 0; r < 7; ++r) {
                    v[2 * r]     = __hip_atomic_load(&ssrc[ridx[r]],     __ATOMIC_RELAXED, __HIP_MEMORY_SCOPE_AGENT);
                    v[2 * r + 1] = __hip_atomic_load(&ssrc[ridx[r] + 1], __ATOMIC_RELAXED, __HIP_MEMORY_SCOPE_AGENT);
                }
            }
            bool ok = true;
            #pragma unroll
            for (int p = 0; p < 14; ++p) ok &= ((v[p] & 0xFFFFu) == exptag);
            if (ok) break;
            if (++round > 512) __builtin_amdgcn_s_sleep(2);   // paranoia only
        }
        // stage remote h into this parity's LDS tile
        #pragma unroll
        for (int r = 0; r < 7; ++r) {
            const int rbk = (nb + 1 + r) & 7;
            const int c0  = rbk * 128 + pc0;
            const uint32_t pk = (v[2 * r] >> 16) | (v[2 * r + 1] & 0xFFFF0000u);
            *(uint32_t*)(htile[cur] + pb * 2048 + ((c0 * 2) ^ (pb << 4))) = pk;
        }
        __syncthreads();   // htile[cur] complete (remote staged + own from t-1)

        // --- xp prefetch for NEXT step (off the poll's critical path)
        float xnext[4];
        if (t < 511) {
            #pragma unroll
            for (int i = 0; i < 4; ++i)
                xnext[i] = out[((size_t)(gb0 + r4b + i) * 512 + (t + 1)) * 1024 + col];
        }

        // --- phase B: acc = h . Wh[col]^T over full K, 4 interleaved chains
        f32x4 a0 = (f32x4){0.f,0.f,0.f,0.f}, a1 = a0, a2 = a0, a3 = a0;
        {
            const int b_  = lane & 7;
            const int kbx = (lane >> 4) << 4;
            const int swz = b_ << 4;
            const uint8_t* hb = htile[cur] + b_ * 2048;
            #pragma unroll
            for (int kt = 0; kt < 32; kt += 4) {
                const bf16x8 f0 = *(const bf16x8*)(hb + (((kt    ) * 64 + kbx) ^ swz));
                const bf16x8 f1 = *(const bf16x8*)(hb + (((kt + 1) * 64 + kbx) ^ swz));
                const bf16x8 f2 = *(const bf16x8*)(hb + (((kt + 2) * 64 + kbx) ^ swz));
                const bf16x8 f3 = *(const bf16x8*)(hb + (((kt + 3) * 64 + kbx) ^ swz));
                a0 = __builtin_amdgcn_mfma_f32_16x16x32_bf16(f0, whf[kt    ], a0, 0, 0, 0);
                a1 = __builtin_amdgcn_mfma_f32_16x16x32_bf16(f1, whf[kt + 1], a1, 0, 0, 0);
                a2 = __builtin_amdgcn_mfma_f32_16x16x32_bf16(f2, whf[kt + 2], a2, 0, 0, 0);
                a3 = __builtin_amdgcn_mfma_f32_16x16x32_bf16(f3, whf[kt + 3], a3, 0, 0, 0);
            }
        }

        // --- phase C: lanes<32 publish h (fast store first, then slow);
        // lanes>=32 (duplicate C fragment) write out[] concurrently.
        float pre[4], hn[4];
        #pragma unroll
        for (int i = 0; i < 4; ++i) {
            pre[i] = ((a0[i] + a1[i]) + (a2[i] + a3[i])) + xpv[i];
            hn[i]  = fast_tanh(pre[i]);
        }
        if (lane < 32) {
            if (t < 511) {
                uint32_t hu[4];
                #pragma unroll
                for (int i = 0; i < 4; ++i) hu[i] = f2bf(hn[i]);
                if (dual) {
                    #pragma unroll
                    for (int i = 0; i < 4; ++i)
                        ((volatile uint32_t*)fdst)[(gb0 + r4b + i) * 1024 + col] = (hu[i] << 16) | ntag;
                }
                #pragma unroll
                for (int i = 0; i < 4; ++i)
                    __hip_atomic_store(&sdst[(gb0 + r4b + i) * 1024 + col], (hu[i] << 16) | ntag,
                                       __ATOMIC_RELAXED, __HIP_MEMORY_SCOPE_AGENT);
                // own slice -> next parity's LDS tile (never crosses global)
                #pragma unroll
                for (int i = 0; i < 4; ++i)
                    *(uint16_t*)(htile[cur ^ 1] + (r4b + i) * 2048 + ((col * 2) ^ ((r4b + i) << 4))) = (uint16_t)f2bf(hn[i]);
            }
        } else {
            #pragma unroll
            for (int i = 0; i < 4; ++i) {
                out[((size_t)(gb0 + r4b + i) * 512 + t) * 1024 + col] = pre[i];
                if (t == 511) hfin[(size_t)(gb0 + r4b + i) * 1024 + col] = hn[i];
            }
        }
        #pragma unroll
        for (int i = 0; i < 4; ++i) xpv[i] = xnext[i];
    }
}

// ---------------------------------------------------------------------------
extern "C" void kernel_launch(void* const* d_in, const int* in_sizes, int n_in,
                              void* d_out, int out_size, void* d_ws, size_t ws_size,
                              hipStream_t stream) {
    const float* x   = (const float*)d_in[0];   // [64,512,512]
    const float* h0_ = (const float*)d_in[1];   // [64,1024]
    const float* Wx  = (const float*)d_in[2];   // [1024,512]
    const float* bx  = (const float*)d_in[3];   // [1024]
    const float* Wh  = (const float*)d_in[4];   // [1024,1024]
    const float* bh  = (const float*)d_in[5];   // [1024]
    float* out  = (float*)d_out;                         // [64,512,1024] pre
    float* hfin = out + (size_t)64 * 512 * 1024;         // [64,1024]

    const size_t HALF_W  = (size_t)2 * 64 * 1024;        // words per buffer
    const size_t BUF_B   = HALF_W * sizeof(uint32_t);    // 512 KB
    const size_t CLAIM_B = 512;
    const int dual = (ws_size >= CLAIM_B + 2 * BUF_B) ? 1 : 0;

    uint32_t* claim;
    uint32_t* fbuf;
    uint32_t* sbuf;
    if (dual) {
        claim = (uint32_t*)d_ws;
        fbuf  = claim + CLAIM_B / sizeof(uint32_t);
        sbuf  = fbuf + HALF_W;
        hipMemsetAsync(claim, 0x00, CLAIM_B, stream);
        hipMemsetAsync(fbuf, 0xFF, 2 * BUF_B, stream);   // no tag matches 1..513
    } else {
        claim = (uint32_t*)d_ws;
        fbuf  = (uint32_t*)d_ws;
        sbuf  = fbuf;
        hipMemsetAsync(d_ws, 0xFF, BUF_B, stream);
    }

    xproj_gemm<<<dim3(2048), dim3(256), 0, stream>>>(x, Wx, bx, bh, out);
    rnn_scan<<<dim3(dual ? 256 : 64), dim3(512), 0, stream>>>(
        h0_, Wh, out, hfin, claim, fbuf, sbuf, dual);
}